// Round 5
// baseline (3595.583 us; speedup 1.0000x reference)
//
#include <hip/hip_runtime.h>
#include <math.h>

#define Bsz 128
#define Tsz 512
#define Hsz 1024
#define NM  8
#define MS  128
#define NT  1024
#define NPAIR 36

// ---------------------------------------------------------------------------
// Retile W_hh into block-major WB.
//   pair p = tri index of (r,c), r<=c: p = c(c+1)/2 + r.
//   p==0 : WB[0][row*128 + j]  (j-fastest: feeds per-row register cache)
//   p>=1 : WB[p][j*128 + row]  (row-fastest: lane-coalesced float4-of-rows)
// ---------------------------------------------------------------------------
__global__ __launch_bounds__(256)
void retile_whh(const float* __restrict__ W, float* __restrict__ WB) {
    __shared__ float tile[MS][MS + 1];
    const int p = blockIdx.x;
    int c = 0;
    while ((c + 1) * (c + 2) / 2 <= p) ++c;
    const int r = p - c * (c + 1) / 2;
    const int t = threadIdx.x;
    if (p == 0) {
        for (int idx = t; idx < MS * MS; idx += 256) {
            const int row = idx >> 7, j = idx & (MS - 1);
            WB[idx] = W[row * Hsz + j];
        }
        return;
    }
    for (int idx = t; idx < MS * MS; idx += 256) {
        const int row = idx >> 7, j = idx & (MS - 1);
        tile[row][j] = W[(size_t)(r * MS + row) * Hsz + c * MS + j];
    }
    __syncthreads();
    float* wb = WB + (size_t)p * MS * MS;
    for (int idx = t; idx < MS * MS; idx += 256) {
        const int j = idx >> 7, row = idx & (MS - 1);
        wb[idx] = tile[row][j];
    }
}

__device__ __forceinline__ float fast_tanh(float x) {
    const float e = __expf(2.0f * x);
    return 1.0f - 2.0f * __builtin_amdgcn_rcpf(e + 1.0f);
}

// ---------------------------------------------------------------------------
// Persistent per-batch-element Clockwork RNN. grid=128, block=1024 (16 waves).
//
// P1: one row per thread (g = tid < nrows); fused per-module fc-output
//     wave reduction into WP[wave].
// refresh00 (threads 0..511): row = tid>>2, jc = tid&3; 32 register weights
//     per thread (rotated chunk order per jc: bank-conflict-free h reads);
//     quad shfl_xor reduce -> Sp1[0][row] single value.
// refresh_hi (threads 512..1023): 4 pairs concurrently; thread owns 4 rows x
//     32 j's, quad shfl_xor reduce over jq -> Sp1[p][row4] float4.
// Sp1[p][row]: ONE value per (pair,row) -> P1 reads (8-r) scalars per row.
// Thread0 keeps O[m] (per-module fc contribution) + running sum in registers.
// ---------------------------------------------------------------------------
__global__ __launch_bounds__(NT, 1)
void cwrnn_kernel(const float* __restrict__ x,      // [B, T+1, 2, 1]
                  const float* __restrict__ W_ih,   // [H, 2]
                  const float* __restrict__ fc_w,   // [2, H]
                  const float* __restrict__ fc_b,   // [2]
                  const float* __restrict__ enc_w,  // [H, 2]
                  const float* __restrict__ WB,     // retiled W_hh blocks
                  float* __restrict__ out)          // [B, T, 2]
{
    __shared__ float  h_s[Hsz];
    __shared__ float  Sp1[NPAIR][MS];     // 18 KB, single value per (p,row)
    __shared__ float2 x_s[Tsz + 1];
    __shared__ float2 wih_s[Hsz];
    __shared__ float2 fcw_s[Hsz];
    __shared__ float  out_s[Tsz * 2];
    __shared__ float2 WP[16];             // per-wave fc partials

    const int tid  = threadIdx.x;
    const int lane = tid & 63;
    const int wave = tid >> 6;
    const int b    = blockIdx.x;

    const float2* xb = (const float2*)(x + (size_t)b * (Tsz + 1) * 2);

    for (int i = tid; i < Tsz + 1; i += NT) x_s[i] = xb[i];
    for (int i = tid; i < Hsz; i += NT) wih_s[i] = ((const float2*)W_ih)[i];
    for (int i = tid; i < Hsz; i += NT)
        fcw_s[i] = make_float2(fc_w[i], fc_w[Hsz + i]);
    const float fb0 = fc_b[0], fb1 = fc_b[1];

    // ---- (0,0) register cache, chunk order rotated by jc ----
    const int row00 = (tid & 511) >> 2;   // 0..127 (threads < 512)
    const int jc    = tid & 3;
    float4 w00[8];
    if (tid < 512) {
        #pragma unroll
        for (int u = 0; u < 8; ++u) {
            const int uu = (u + 2 * jc) & 7;
            w00[u] = *(const float4*)(WB + row00 * MS + jc * 32 + uu * 4);
        }
    }

    // ---- refresh_hi mapping (threads >= 512) ----
    const int hslot = (tid >> 7) & 3;     // pair slot 0..3
    const int hs    = tid & 127;
    const int hrq   = (hs >> 2) << 2;     // row base 0,4,...,124
    const int hjq   = hs & 3;             // j quarter

    // ---- h0 = x[:,0] @ enc_w.T ----
    {
        const float2 x0 = xb[0];
        for (int i = tid; i < Hsz; i += NT) {
            const float2 ew = ((const float2*)enc_w)[i];
            h_s[i] = x0.x * ew.x + x0.y * ew.y;
        }
    }
    __syncthreads();

    auto refresh00 = [&]() {
        if (tid < 512) {
            float a = 0.f;
            #pragma unroll
            for (int u = 0; u < 8; ++u) {
                const int uu = (u + 2 * jc) & 7;      // rotation: distinct banks per jc
                const float4 hv = *(const float4*)(h_s + jc * 32 + uu * 4);
                a += w00[u].x * hv.x + w00[u].y * hv.y + w00[u].z * hv.z + w00[u].w * hv.w;
            }
            a += __shfl_xor(a, 1, 64);
            a += __shfl_xor(a, 2, 64);
            if (jc == 0) Sp1[0][row00] = a;
        }
    };

    auto refresh_hi = [&](int P) {
        if (tid >= 512) {
            for (int p = 1 + hslot; p < P; p += 4) {
                const int c = (int)((sqrtf((float)(8 * p + 1)) - 1.0f) * 0.5f);
                const float* wbp = WB + (size_t)p * MS * MS + hrq;
                const float* hc  = h_s + c * MS;
                float4 acc = {0.f, 0.f, 0.f, 0.f};
                #pragma unroll 8
                for (int jj = 0; jj < 32; ++jj) {
                    const int j = hjq * 32 + ((jj + hjq * 8) & 31);  // rotated banks
                    const float hj = hc[j];
                    const float4 wv = *(const float4*)(wbp + j * MS);
                    acc.x += wv.x * hj; acc.y += wv.y * hj;
                    acc.z += wv.z * hj; acc.w += wv.w * hj;
                }
                acc.x += __shfl_xor(acc.x, 1, 64); acc.y += __shfl_xor(acc.y, 1, 64);
                acc.z += __shfl_xor(acc.z, 1, 64); acc.w += __shfl_xor(acc.w, 1, 64);
                acc.x += __shfl_xor(acc.x, 2, 64); acc.y += __shfl_xor(acc.y, 2, 64);
                acc.z += __shfl_xor(acc.z, 2, 64); acc.w += __shfl_xor(acc.w, 2, 64);
                if (hjq == 0) *(float4*)&Sp1[p][hrq] = acc;
            }
        }
    };

    refresh00();
    refresh_hi(NPAIR);
    __syncthreads();

    // thread0's cached per-module fc contributions + running total
    float o0r[NM] = {0,0,0,0,0,0,0,0};
    float o1r[NM] = {0,0,0,0,0,0,0,0};
    float Sall0 = 0.f, Sall1 = 0.f;

    for (int t = 0; t < Tsz; ++t) {
        const int A = (t == 0) ? 7 : min(__ffs(t) - 1, 7);
        const int nrows = (A + 1) * MS;
        const float2 xt = x_s[t + 1];

        // ---- P1: h update + fused per-wave fc partial ----
        if (tid < nrows) {
            const int r  = tid >> 7;              // wave-uniform
            const int il = tid & (MS - 1);
            const float2 wih2 = wih_s[tid];
            float pre = xt.x * wih2.x + xt.y * wih2.y;
            #pragma unroll
            for (int c = 0; c < NM; ++c)
                if (c >= r)                        // wave-uniform branch
                    pre += Sp1[c * (c + 1) / 2 + r][il];
            const float h = fast_tanh(pre);
            h_s[tid] = h;
            const float2 fw = fcw_s[tid];
            float p0 = h * fw.x, p1 = h * fw.y;
            #pragma unroll
            for (int o = 32; o > 0; o >>= 1) {
                p0 += __shfl_down(p0, o, 64);
                p1 += __shfl_down(p1, o, 64);
            }
            if (lane == 0) WP[wave] = make_float2(p0, p1);
        }
        __syncthreads();

        // ---- refresh columns 0..A (disjoint thread groups, concurrent) ----
        refresh00();
        refresh_hi((A + 1) * (A + 2) / 2);

        // ---- thread0: update O[m] for modules 0..A, emit out[t] ----
        if (tid == 0) {
            #pragma unroll
            for (int m = 0; m < NM; ++m) {
                if (m <= A) {
                    const float2 wa = WP[2 * m], wb2 = WP[2 * m + 1];
                    const float n0 = wa.x + wb2.x, n1 = wa.y + wb2.y;
                    Sall0 += n0 - o0r[m]; Sall1 += n1 - o1r[m];
                    o0r[m] = n0; o1r[m] = n1;
                }
            }
            out_s[2 * t]     = Sall0 + fb0;
            out_s[2 * t + 1] = Sall1 + fb1;
        }
        __syncthreads();
        // WP WAR: next P1 write is after this barrier; thread0 read done. Safe.
    }

    float* outb = out + (size_t)b * Tsz * 2;
    for (int i = tid; i < Tsz * 2; i += NT) outb[i] = out_s[i];
}

// ---------------------------------------------------------------------------
extern "C" void kernel_launch(void* const* d_in, const int* in_sizes, int n_in,
                              void* d_out, int out_size, void* d_ws, size_t ws_size,
                              hipStream_t stream) {
    const float* x     = (const float*)d_in[0];
    const float* W_ih  = (const float*)d_in[1];
    const float* W_hh  = (const float*)d_in[2];
    const float* fc_w  = (const float*)d_in[3];
    const float* fc_b  = (const float*)d_in[4];
    const float* enc_w = (const float*)d_in[5];
    float* outp = (float*)d_out;
    float* WB   = (float*)d_ws;            // 36*16384*4 = 2.25 MB

    retile_whh<<<NPAIR, 256, 0, stream>>>(W_hh, WB);
    cwrnn_kernel<<<Bsz, NT, 0, stream>>>(x, W_ih, fc_w, fc_b, enc_w, WB, outp);
}